// Round 1
// baseline (574.488 us; speedup 1.0000x reference)
//
#include <hip/hip_runtime.h>

// B=256 rows, D=131072 cols, all fp32.
// p = max over rows of (1-mean|corr|) * (row_mse/total_mse) * (row_unique/total_unique)
// out = x * (noise >= p) / (1-p)
//
// Sufficient stats: G = x x^T (256x256), rowsums, per-row presence bitmask of rint(x).
// cov_ik = (G_ik - rs_i rs_k / D) / (D-1)
// row_mse_i = (G_ii - (2/B) * sum_k G_ik + (sum_all G)/B^2) / D
//
// ws layout (bytes):
//   0      : presence  u64[256]            (zeroed by init, atomicOr target)
//   2048   : pscal     double[8]           ([0]=p f64, bytes8..11 p f32, 12..15 1/(1-p) f32)
//   4096   : rowsumPart float[256*256]     ([blk*256 + row])
//   266240 : G32       float[256*256]      (path B only: fp32 atomic target, zeroed)
//   528384 : Gf64      double[256*256]     (path A: reduced Gram)
//   1052672: Gpart     float[256*65536]    (path A: per-block partial Grams, 64 MB)

#define NB 256
#define DD 131072
#define CHUNK 512      // columns per gram block
#define TC 32          // columns per LDS subtile
#define NSUB (CHUNK / TC)   // 16 subtiles
#define LDS_S 260      // padded row stride (floats) in transposed tile

__global__ void init_kernel(unsigned long long* __restrict__ pres,
                            double* __restrict__ pscal,
                            float* __restrict__ g32, int zeroG) {
    int t = blockIdx.x * blockDim.x + threadIdx.x;
    if (t < 256) pres[t] = 0ull;
    if (t < 8) pscal[t] = 0.0;
    if (zeroG) {
        for (int j = t; j < 65536; j += gridDim.x * blockDim.x) g32[j] = 0.0f;
    }
}

__device__ __forceinline__ unsigned long long pres_bit(float v) {
    int bi = (int)rintf(v);               // round-half-even, matches np.round
    bi = bi < -32 ? -32 : (bi > 31 ? 31 : bi);
    return 1ull << (bi + 32);
}

// 256 blocks x 1024 threads. Block b owns columns [b*512, (b+1)*512).
// Thread (ti,tk) = (t&31, t>>5) accumulates 8x8 subtile of G in registers.
__global__ __launch_bounds__(1024) void gram_kernel(
    const float* __restrict__ x,
    float* __restrict__ gpart,          // path A
    float* __restrict__ g32,            // path B
    float* __restrict__ rowsumPart,
    unsigned long long* __restrict__ gpres,
    int pathA) {
    __shared__ float ldsT[TC * LDS_S];            // transposed tile: [col][row]
    __shared__ float rsbuf[1024];
    __shared__ unsigned long long maskbuf[1024];

    const int t  = threadIdx.x;
    const int ti = t & 31;
    const int tk = t >> 5;
    const int r  = t >> 2;     // staging row (fixed per thread)
    const int q  = t & 3;      // staging col group
    const int blk = blockIdx.x;
    const size_t c0blk = (size_t)blk * CHUNK;

    float acc[8][8];
#pragma unroll
    for (int a = 0; a < 8; ++a)
#pragma unroll
        for (int b = 0; b < 8; ++b) acc[a][b] = 0.0f;

    float rsum = 0.0f;
    unsigned long long mask = 0ull;

    for (int s = 0; s < NSUB; ++s) {
        // ---- stage 256 x 32 tile, transposed into LDS ----
        const float* xp = x + (size_t)r * DD + c0blk + (size_t)s * TC;
#pragma unroll
        for (int u = 0; u < 2; ++u) {
            const int lc = q * 8 + u * 4;
            float4 v = *(const float4*)(xp + lc);
            rsum += v.x + v.y + v.z + v.w;
            mask |= pres_bit(v.x) | pres_bit(v.y) | pres_bit(v.z) | pres_bit(v.w);
            ldsT[(lc + 0) * LDS_S + r] = v.x;
            ldsT[(lc + 1) * LDS_S + r] = v.y;
            ldsT[(lc + 2) * LDS_S + r] = v.z;
            ldsT[(lc + 3) * LDS_S + r] = v.w;
        }
        __syncthreads();

        // ---- 8x8 outer-product accumulation over 32 columns ----
#pragma unroll 2
        for (int lc = 0; lc < TC; ++lc) {
            const float4* ap = (const float4*)&ldsT[lc * LDS_S + ti * 8];
            const float4* bp = (const float4*)&ldsT[lc * LDS_S + tk * 8];
            float4 a0 = ap[0], a1 = ap[1];
            float4 b0 = bp[0], b1 = bp[1];
            float av[8] = {a0.x, a0.y, a0.z, a0.w, a1.x, a1.y, a1.z, a1.w};
            float bv[8] = {b0.x, b0.y, b0.z, b0.w, b1.x, b1.y, b1.z, b1.w};
#pragma unroll
            for (int a = 0; a < 8; ++a)
#pragma unroll
                for (int b = 0; b < 8; ++b) acc[a][b] += av[a] * bv[b];
        }
        __syncthreads();
    }

    // ---- per-block rowsum + presence reduction ----
    rsbuf[t] = rsum;
    maskbuf[t] = mask;
    __syncthreads();
    if (t < 256) {
        float s4 = rsbuf[4 * t] + rsbuf[4 * t + 1] + rsbuf[4 * t + 2] + rsbuf[4 * t + 3];
        unsigned long long m4 = maskbuf[4 * t] | maskbuf[4 * t + 1] |
                                maskbuf[4 * t + 2] | maskbuf[4 * t + 3];
        rowsumPart[blk * 256 + t] = s4;
        atomicOr(&gpres[t], m4);
    }

    // ---- emit partial Gram ----
    if (pathA) {
        // thread-contiguous (coalesced); gred undoes the permutation
        float4* dst4 = (float4*)(gpart + (size_t)blk * 65536 + (size_t)t * 64);
#pragma unroll
        for (int a = 0; a < 8; ++a) {
            dst4[a * 2 + 0] = make_float4(acc[a][0], acc[a][1], acc[a][2], acc[a][3]);
            dst4[a * 2 + 1] = make_float4(acc[a][4], acc[a][5], acc[a][6], acc[a][7]);
        }
    } else {
#pragma unroll
        for (int a = 0; a < 8; ++a)
#pragma unroll
            for (int b = 0; b < 8; ++b)
                atomicAdd(&g32[(ti * 8 + a) * 256 + (tk * 8 + b)], acc[a][b]);
    }
}

// Reduce 256 partial Grams in fp64; undo the thread-linear permutation.
__global__ __launch_bounds__(256) void gred_kernel(const float* __restrict__ gpart,
                                                   double* __restrict__ gf64) {
    int j = blockIdx.x * 256 + threadIdx.x;
    double s = 0.0;
    for (int p = 0; p < 256; ++p) s += (double)gpart[(size_t)p * 65536 + j];
    int tt = j >> 6, idx = j & 63;
    int ti = tt & 31, tk = tt >> 5, a = idx >> 3, b = idx & 7;
    gf64[(ti * 8 + a) * 256 + (tk * 8 + b)] = s;
}

// Single block, 256 threads, all fp64: corr, mse, uniques, p.
__global__ __launch_bounds__(256) void reduce_kernel(
    const double* __restrict__ gf64, const float* __restrict__ g32,
    const float* __restrict__ rsp, const unsigned long long* __restrict__ pres,
    double* __restrict__ pscal, int pathA) {
    __shared__ double rs[256], sd[256], f1s[256], sumg[256], rmse[256], cand[256];
    __shared__ double Ssh, tmse_sh;
    __shared__ int totu_sh;
    const double Dd = (double)DD;
    int i = threadIdx.x;

    double s = 0.0;
    for (int p = 0; p < 256; ++p) s += (double)rsp[p * 256 + i];
    rs[i] = s;
    __syncthreads();

    double gii = pathA ? gf64[i * 256 + i] : (double)g32[i * 256 + i];
    double covii = (gii - rs[i] * rs[i] / Dd) / (Dd - 1.0);
    sd[i] = sqrt(covii);
    __syncthreads();

    double f1 = 0.0, sg = 0.0;
    for (int k = 0; k < 256; ++k) {
        // read column i (== row i by symmetry) so lanes coalesce
        double gik = pathA ? gf64[k * 256 + i] : (double)g32[k * 256 + i];
        sg += gik;
        double cov = (gik - rs[i] * rs[k] / Dd) / (Dd - 1.0);
        double corr = cov / (sd[i] * sd[k]);
        corr = fmin(1.0, fmax(-1.0, corr));
        f1 += fabs(corr);
    }
    f1s[i] = f1 / 256.0;
    sumg[i] = sg;
    __syncthreads();

    if (i == 0) {
        double S = 0.0;
        for (int k = 0; k < 256; ++k) S += sumg[k];
        Ssh = S;
        unsigned long long m = 0ull;
        for (int k = 0; k < 256; ++k) m |= pres[k];
        totu_sh = __popcll(m);
    }
    __syncthreads();

    rmse[i] = (gii - (2.0 / 256.0) * sumg[i] + Ssh / (256.0 * 256.0)) / Dd;
    __syncthreads();
    if (i == 0) {
        double tm = 0.0;
        for (int k = 0; k < 256; ++k) tm += rmse[k];
        tmse_sh = tm;
    }
    __syncthreads();

    double f3 = (double)__popcll(pres[i]) / (double)totu_sh;
    cand[i] = (1.0 - f1s[i]) * (rmse[i] / tmse_sh) * f3;
    __syncthreads();

    if (i == 0) {
        double p = 0.0;
        for (int k = 0; k < 256; ++k) p = fmax(p, cand[k]);
        pscal[0] = p;
        float* pf = (float*)(pscal + 1);
        pf[0] = (float)p;
        pf[1] = (float)(1.0 / (1.0 - p));
    }
}

__global__ __launch_bounds__(256) void dropout_kernel(
    const float4* __restrict__ x, const float4* __restrict__ n,
    float4* __restrict__ o, const double* __restrict__ pscal) {
    const float* pp = (const float*)(pscal + 1);
    const float pf = pp[0];
    const float inv = pp[1];
    int idx = blockIdx.x * 256 + threadIdx.x;
    float4 xv = x[idx];
    float4 nv = n[idx];
    float4 ov;
    ov.x = (nv.x >= pf) ? xv.x * inv : 0.0f;
    ov.y = (nv.y >= pf) ? xv.y * inv : 0.0f;
    ov.z = (nv.z >= pf) ? xv.z * inv : 0.0f;
    ov.w = (nv.w >= pf) ? xv.w * inv : 0.0f;
    o[idx] = ov;
}

extern "C" void kernel_launch(void* const* d_in, const int* in_sizes, int n_in,
                              void* d_out, int out_size, void* d_ws, size_t ws_size,
                              hipStream_t stream) {
    const float* x = (const float*)d_in[0];
    const float* noise = (const float*)d_in[1];
    float* out = (float*)d_out;
    char* ws = (char*)d_ws;

    unsigned long long* pres = (unsigned long long*)(ws + 0);
    double* pscal = (double*)(ws + 2048);
    float* rsp = (float*)(ws + 4096);
    float* g32 = (float*)(ws + 266240);
    double* gf64 = (double*)(ws + 528384);
    float* gpart = (float*)(ws + 1052672);

    const size_t needA = 1052672 + (size_t)256 * 65536 * sizeof(float);  // ~68.2 MB
    const int pathA = (ws_size >= needA) ? 1 : 0;

    init_kernel<<<64, 256, 0, stream>>>(pres, pscal, g32, !pathA);
    gram_kernel<<<NB, 1024, 0, stream>>>(x, gpart, g32, rsp, pres, pathA);
    if (pathA) gred_kernel<<<256, 256, 0, stream>>>(gpart, gf64);
    reduce_kernel<<<1, 256, 0, stream>>>(gf64, g32, rsp, pres, pscal, pathA);
    dropout_kernel<<<(NB * DD) / (4 * 256), 256, 0, stream>>>(
        (const float4*)x, (const float4*)noise, (float4*)out, pscal);
}

// Round 2
// 432.863 us; speedup vs baseline: 1.3272x; 1.3272x over previous
//
#include <hip/hip_runtime.h>

// B=256 rows, D=131072 cols, fp32 in/out.
// p = max over rows of (1-mean|corr|) * (row_mse/total_mse) * (row_unique/total_unique)
// out = x * (noise >= p) / (1-p)
//
// Gram G = x x^T via MFMA bf16x3: x = hi + lo (bf16 RN splits),
// G ~= hi*hi + hi*lo + lo*hi  (fp32 MFMA accum), diagonal corrected by +sum(lo^2).
// cov_ik = (G_ik - rs_i rs_k / D) / (D-1)
// row_mse_i = (G_ii - (2/B) sum_k G_ik + (sum G)/B^2) / D
//
// ws layout (bytes):
//   0      : presence  u64[256]
//   2048   : pscal     double[8]  ([0]=p f64; bytes 8..11 p f32; 12..15 1/(1-p) f32)
//   4096   : rowsumPart f32[256*256]
//   266240 : loloPart   f32[256*256]
//   528384 : g32        f32[256*256]   (path B: fp32 atomic target)
//   790528 : gf64       double[256*256](path A: reduced Gram)
//   1314816: gpart      f32[256*65536] (path A: per-block partial Grams, 64 MB)

#define BR 256
#define DD 131072
#define KBLK 512            // K columns per gram block
#define KS 32               // K columns per LDS stage (= one 16x16x32 k-step)
#define NSTG (KBLK / KS)    // 16 stages
#define LSTR 40             // LDS row stride in bf16 elems (32 + 8 pad) -> conflict-free frags

typedef float f32x4 __attribute__((ext_vector_type(4)));
typedef __bf16 bf16x8 __attribute__((ext_vector_type(8)));
typedef __bf16 bf16x4 __attribute__((ext_vector_type(4)));

__global__ void init_kernel(unsigned long long* __restrict__ pres,
                            double* __restrict__ pscal,
                            float* __restrict__ g32, int zeroG) {
    int t = blockIdx.x * blockDim.x + threadIdx.x;
    if (t < 256) pres[t] = 0ull;
    if (t < 8) pscal[t] = 0.0;
    if (zeroG) {
        for (int j = t; j < 65536; j += gridDim.x * blockDim.x) g32[j] = 0.0f;
    }
}

__device__ __forceinline__ unsigned long long pres_bit(float v) {
    int bi = (int)rintf(v);               // round-half-even, matches np.round
    bi = bi < -32 ? -32 : (bi > 31 ? 31 : bi);
    return 1ull << (bi + 32);
}

__device__ __forceinline__ void conv4(float4 v, __bf16* hi, __bf16* lo,
                                      float& rsum, float& lolo,
                                      unsigned long long& mask) {
    float vv[4] = {v.x, v.y, v.z, v.w};
    bf16x4 hv, lv;
#pragma unroll
    for (int k = 0; k < 4; ++k) {
        float f = vv[k];
        __bf16 h = (__bf16)f;             // RN
        float hf = (float)h;
        float lof = f - hf;               // exact (exponents adjacent)
        __bf16 l = (__bf16)lof;
        float lf = (float)l;
        hv[k] = h;
        lv[k] = l;
        rsum += f;
        lolo += lf * lf;
        mask |= pres_bit(f);
    }
    *(bf16x4*)hi = hv;
    *(bf16x4*)lo = lv;
}

// 256 blocks x 1024 threads, 1 block/CU. Block b owns K columns [b*512, b*512+512).
// 16 waves in a 4x4 grid; each wave computes a 64x64 output tile as 4x4 MFMA
// 16x16x32 tiles, 3 MFMA passes (hi*hi, hi*lo, lo*hi) into one fp32 accumulator.
__global__ __launch_bounds__(1024) void gram_kernel(
    const float* __restrict__ x,
    float* __restrict__ gpart,
    float* __restrict__ g32,
    float* __restrict__ rowsumPart,
    float* __restrict__ loloPart,
    unsigned long long* __restrict__ gpres,
    int pathA) {
    __shared__ __bf16 ldsHi[BR * LSTR];
    __shared__ __bf16 ldsLo[BR * LSTR];
    __shared__ float rsbuf[1024];
    __shared__ float lolobuf[1024];
    __shared__ unsigned long long maskbuf[1024];

    const int t = threadIdx.x;
    const int r = t >> 2;        // staging row (fixed per thread)
    const int q = t & 3;         // staging quarter within row
    const int lane = t & 63;
    const int wv = t >> 6;       // wave 0..15
    const int wr = wv >> 2;      // wave row tile group
    const int wc = wv & 3;       // wave col tile group
    const int fr = lane & 15;    // fragment row (A/B operand m/n index)
    const int fq = lane >> 4;    // fragment quad (k group)
    const int blk = blockIdx.x;

    const float* xrow = x + (size_t)r * DD + (size_t)blk * KBLK;

    f32x4 acc[4][4];
#pragma unroll
    for (int i = 0; i < 4; ++i)
#pragma unroll
        for (int j = 0; j < 4; ++j) acc[i][j] = (f32x4){0.f, 0.f, 0.f, 0.f};

    float rsum = 0.f, lolo = 0.f;
    unsigned long long mask = 0ull;

    // LDS fragment base pointers (A operand: lane holds A[m=lane&15][k=fq*8+j])
    const __bf16* aHi = ldsHi + (wr * 64 + fr) * LSTR + fq * 8;
    const __bf16* aLo = ldsLo + (wr * 64 + fr) * LSTR + fq * 8;
    const __bf16* bHi = ldsHi + (wc * 64 + fr) * LSTR + fq * 8;
    const __bf16* bLo = ldsLo + (wc * 64 + fr) * LSTR + fq * 8;

    // register prefetch of stage 0
    float4 pre0 = *(const float4*)(xrow + q * 4);
    float4 pre1 = *(const float4*)(xrow + q * 4 + 16);

    for (int s = 0; s < NSTG; ++s) {
        __syncthreads();   // prior stage's LDS reads complete
        conv4(pre0, &ldsHi[r * LSTR + q * 4], &ldsLo[r * LSTR + q * 4], rsum, lolo, mask);
        conv4(pre1, &ldsHi[r * LSTR + q * 4 + 16], &ldsLo[r * LSTR + q * 4 + 16], rsum, lolo, mask);
        __syncthreads();   // stage visible to all waves

        if (s + 1 < NSTG) {   // issue next stage's loads; latency hidden by MFMA phase
            pre0 = *(const float4*)(xrow + (s + 1) * KS + q * 4);
            pre1 = *(const float4*)(xrow + (s + 1) * KS + q * 4 + 16);
        }

        bf16x8 ah[4], al[4];
#pragma unroll
        for (int i = 0; i < 4; ++i) {
            ah[i] = *(const bf16x8*)(aHi + i * 16 * LSTR);
            al[i] = *(const bf16x8*)(aLo + i * 16 * LSTR);
        }
#pragma unroll
        for (int j = 0; j < 4; ++j) {
            bf16x8 bh = *(const bf16x8*)(bHi + j * 16 * LSTR);
            bf16x8 bl = *(const bf16x8*)(bLo + j * 16 * LSTR);
#pragma unroll
            for (int i = 0; i < 4; ++i) {
                acc[i][j] = __builtin_amdgcn_mfma_f32_16x16x32_bf16(ah[i], bh, acc[i][j], 0, 0, 0);
                acc[i][j] = __builtin_amdgcn_mfma_f32_16x16x32_bf16(ah[i], bl, acc[i][j], 0, 0, 0);
                acc[i][j] = __builtin_amdgcn_mfma_f32_16x16x32_bf16(al[i], bh, acc[i][j], 0, 0, 0);
            }
        }
    }

    // ---- rowsum / lolo / presence block reduction ----
    __syncthreads();
    rsbuf[t] = rsum;
    lolobuf[t] = lolo;
    maskbuf[t] = mask;
    __syncthreads();
    if (t < 256) {
        float s4 = rsbuf[4 * t] + rsbuf[4 * t + 1] + rsbuf[4 * t + 2] + rsbuf[4 * t + 3];
        float l4 = lolobuf[4 * t] + lolobuf[4 * t + 1] + lolobuf[4 * t + 2] + lolobuf[4 * t + 3];
        unsigned long long m4 = maskbuf[4 * t] | maskbuf[4 * t + 1] |
                                maskbuf[4 * t + 2] | maskbuf[4 * t + 3];
        rowsumPart[blk * 256 + t] = s4;
        loloPart[blk * 256 + t] = l4;
        atomicOr(&gpres[t], m4);
    }

    // ---- emit Gram tile: C/D layout col=lane&15, row=fq*4+reg (m89-verified) ----
    if (pathA) {
        float* dst = gpart + (size_t)blk * 65536;
#pragma unroll
        for (int i = 0; i < 4; ++i)
#pragma unroll
            for (int j = 0; j < 4; ++j) {
                int row = (wr * 4 + i) * 16 + fq * 4;
                int col = (wc * 4 + j) * 16 + fr;
#pragma unroll
                for (int reg = 0; reg < 4; ++reg)
                    dst[(row + reg) * 256 + col] = acc[i][j][reg];
            }
    } else {
#pragma unroll
        for (int i = 0; i < 4; ++i)
#pragma unroll
            for (int j = 0; j < 4; ++j) {
                int row = (wr * 4 + i) * 16 + fq * 4;
                int col = (wc * 4 + j) * 16 + fr;
#pragma unroll
                for (int reg = 0; reg < 4; ++reg)
                    atomicAdd(&g32[(row + reg) * 256 + col], acc[i][j][reg]);
            }
    }
}

// Reduce 256 partial Grams in fp64 (no permutation needed now).
__global__ __launch_bounds__(256) void gred_kernel(const float* __restrict__ gpart,
                                                   double* __restrict__ gf64) {
    int j = blockIdx.x * 256 + threadIdx.x;
    double s = 0.0;
#pragma unroll 8
    for (int p = 0; p < 256; ++p) s += (double)gpart[(size_t)p * 65536 + j];
    gf64[j] = s;
}

// Single block, 256 threads, all fp64: corr, mse, uniques, p.
__global__ __launch_bounds__(256) void reduce_kernel(
    const double* __restrict__ gf64, const float* __restrict__ g32,
    const float* __restrict__ rsp, const float* __restrict__ lolop,
    const unsigned long long* __restrict__ pres,
    double* __restrict__ pscal, int pathA) {
    __shared__ double rs[256], sd[256], f1s[256], sumg[256], rmse[256], cand[256], gdia[256];
    __shared__ double Ssh, tmse_sh;
    __shared__ int totu_sh;
    const double Dd = (double)DD;
    int i = threadIdx.x;

    double s = 0.0, lol = 0.0;
    for (int p = 0; p < 256; ++p) {
        s += (double)rsp[p * 256 + i];
        lol += (double)lolop[p * 256 + i];
    }
    rs[i] = s;

    double gii = (pathA ? gf64[i * 256 + i] : (double)g32[i * 256 + i]) + lol;
    gdia[i] = gii;
    double covii = (gii - s * s / Dd) / (Dd - 1.0);
    sd[i] = sqrt(covii);
    __syncthreads();

    double f1 = 0.0, sg = 0.0;
    for (int k = 0; k < 256; ++k) {
        double gik = pathA ? gf64[k * 256 + i] : (double)g32[k * 256 + i];
        sg += gik;
        double cov = (gik - rs[i] * rs[k] / Dd) / (Dd - 1.0);
        double corr = cov / (sd[i] * sd[k]);
        corr = fmin(1.0, fmax(-1.0, corr));
        f1 += fabs(corr);
    }
    f1s[i] = f1 / 256.0;
    sumg[i] = sg;
    __syncthreads();

    if (i == 0) {
        double S = 0.0;
        for (int k = 0; k < 256; ++k) S += sumg[k];
        Ssh = S;
        unsigned long long m = 0ull;
        for (int k = 0; k < 256; ++k) m |= pres[k];
        totu_sh = __popcll(m);
    }
    __syncthreads();

    rmse[i] = (gdia[i] - (2.0 / 256.0) * sumg[i] + Ssh / (256.0 * 256.0)) / Dd;
    __syncthreads();
    if (i == 0) {
        double tm = 0.0;
        for (int k = 0; k < 256; ++k) tm += rmse[k];
        tmse_sh = tm;
    }
    __syncthreads();

    double f3 = (double)__popcll(pres[i]) / (double)totu_sh;
    cand[i] = (1.0 - f1s[i]) * (rmse[i] / tmse_sh) * f3;
    __syncthreads();

    if (i == 0) {
        double p = 0.0;
        for (int k = 0; k < 256; ++k) p = fmax(p, cand[k]);
        pscal[0] = p;
        float* pf = (float*)(pscal + 1);
        pf[0] = (float)p;
        pf[1] = (float)(1.0 / (1.0 - p));
    }
}

__global__ __launch_bounds__(256) void dropout_kernel(
    const float4* __restrict__ x, const float4* __restrict__ n,
    float4* __restrict__ o, const double* __restrict__ pscal) {
    const float* pp = (const float*)(pscal + 1);
    const float pf = pp[0];
    const float inv = pp[1];
    int idx = blockIdx.x * 256 + threadIdx.x;
    float4 xv = x[idx];
    float4 nv = n[idx];
    float4 ov;
    ov.x = (nv.x >= pf) ? xv.x * inv : 0.0f;
    ov.y = (nv.y >= pf) ? xv.y * inv : 0.0f;
    ov.z = (nv.z >= pf) ? xv.z * inv : 0.0f;
    ov.w = (nv.w >= pf) ? xv.w * inv : 0.0f;
    o[idx] = ov;
}

extern "C" void kernel_launch(void* const* d_in, const int* in_sizes, int n_in,
                              void* d_out, int out_size, void* d_ws, size_t ws_size,
                              hipStream_t stream) {
    const float* x = (const float*)d_in[0];
    const float* noise = (const float*)d_in[1];
    float* out = (float*)d_out;
    char* ws = (char*)d_ws;

    unsigned long long* pres = (unsigned long long*)(ws + 0);
    double* pscal = (double*)(ws + 2048);
    float* rsp = (float*)(ws + 4096);
    float* lolop = (float*)(ws + 266240);
    float* g32 = (float*)(ws + 528384);
    double* gf64 = (double*)(ws + 790528);
    float* gpart = (float*)(ws + 1314816);

    const size_t needA = 1314816 + (size_t)256 * 65536 * sizeof(float);  // ~68.4 MB
    const int pathA = (ws_size >= needA) ? 1 : 0;

    init_kernel<<<64, 256, 0, stream>>>(pres, pscal, g32, !pathA);
    gram_kernel<<<BR, 1024, 0, stream>>>(x, gpart, g32, rsp, lolop, pres, pathA);
    if (pathA) gred_kernel<<<256, 256, 0, stream>>>(gpart, gf64);
    reduce_kernel<<<1, 256, 0, stream>>>(gf64, g32, rsp, lolop, pres, pscal, pathA);
    dropout_kernel<<<(BR * DD) / (4 * 256), 256, 0, stream>>>(
        (const float4*)x, (const float4*)noise, (float4*)out, pscal);
}

// Round 3
// 359.764 us; speedup vs baseline: 1.5968x; 1.2032x over previous
//
#include <hip/hip_runtime.h>

// B=256 rows, D=131072 cols, fp32 in/out.
// p = max over rows of (1-mean|corr|) * (row_mse/total_mse) * (row_unique/total_unique)
// out = x * (noise >= p) / (1-p)
//
// Gram G = x x^T via MFMA bf16x3: x = hi + lo (bf16 RN splits),
// G ~= hi*hi + hi*lo + lo*hi  (fp32 MFMA accum), diagonal corrected by +sum(lo^2).
// cov_ik = (G_ik - rs_i rs_k / D) / (D-1)
// row_mse_i = (G_ii - (2/B) sum_k G_ik + (sum G)/B^2) / D
//
// ws layout (bytes):
//   0      : pres   u64[256]        (zeroed by init, atomicOr target)
//   2048   : pscal  double[8]       ([0]=p f64; bytes 8..11 p f32; 12..15 1/(1-p) f32)
//   4096   : rsRow  double[256]
//   6144   : sdRow  double[256]
//   8192   : sumgRow double[256]
//   10240  : giiRow double[256]
//   12288  : f1sRow double[256]
//   16384  : rowsumPart f32[256*256]   [row][blk]
//   278528 : loloPart   f32[256*256]   [row][blk]
//   540672 : gf64       double[256*256]
//   1064960: pathA: gpart f32[256*65536] (64 MB) / pathB: g32 f32[65536]

#define BR 256
#define DD 131072
#define KBLK 512            // K columns per gram block
#define KS 32               // K columns per LDS stage (= one 16x16x32 k-step)
#define NSTG (KBLK / KS)    // 16 stages
#define LSTR 40             // LDS row stride in bf16 elems (32 + 8 pad) -> conflict-free frags

typedef float f32x4 __attribute__((ext_vector_type(4)));
typedef __bf16 bf16x8 __attribute__((ext_vector_type(8)));
typedef __bf16 bf16x4 __attribute__((ext_vector_type(4)));

// ---------- small helpers ----------
__device__ __forceinline__ double block_reduce_add_d(double v, double* lds4) {
    for (int o = 32; o > 0; o >>= 1) v += __shfl_down(v, o, 64);
    __syncthreads();
    if ((threadIdx.x & 63) == 0) lds4[threadIdx.x >> 6] = v;
    __syncthreads();
    double r = lds4[0] + lds4[1] + lds4[2] + lds4[3];
    __syncthreads();
    return r;
}

__device__ __forceinline__ double block_reduce_max_d(double v, double* lds4) {
    for (int o = 32; o > 0; o >>= 1) v = fmax(v, __shfl_down(v, o, 64));
    __syncthreads();
    if ((threadIdx.x & 63) == 0) lds4[threadIdx.x >> 6] = v;
    __syncthreads();
    double r = fmax(fmax(lds4[0], lds4[1]), fmax(lds4[2], lds4[3]));
    __syncthreads();
    return r;
}

__device__ __forceinline__ unsigned long long block_reduce_or_u64(
    unsigned long long v, unsigned long long* lds4) {
    for (int o = 32; o > 0; o >>= 1) v |= __shfl_down(v, o, 64);
    __syncthreads();
    if ((threadIdx.x & 63) == 0) lds4[threadIdx.x >> 6] = v;
    __syncthreads();
    unsigned long long r = lds4[0] | lds4[1] | lds4[2] | lds4[3];
    __syncthreads();
    return r;
}

__global__ void init_kernel(unsigned long long* __restrict__ pres,
                            float* __restrict__ g32, int zeroG) {
    int t = blockIdx.x * blockDim.x + threadIdx.x;
    if (t < 256) pres[t] = 0ull;
    if (zeroG) {
        for (int j = t; j < 65536; j += gridDim.x * blockDim.x) g32[j] = 0.0f;
    }
}

__device__ __forceinline__ unsigned long long pres_bit(float v) {
    int bi = (int)rintf(v);               // round-half-even, matches np.round
    bi = bi < -32 ? -32 : (bi > 31 ? 31 : bi);
    return 1ull << (bi + 32);
}

__device__ __forceinline__ void conv4(float4 v, __bf16* hi, __bf16* lo,
                                      float& rsum, float& lolo,
                                      unsigned long long& mask) {
    float vv[4] = {v.x, v.y, v.z, v.w};
    bf16x4 hv, lv;
#pragma unroll
    for (int k = 0; k < 4; ++k) {
        float f = vv[k];
        __bf16 h = (__bf16)f;             // RN
        float hf = (float)h;
        float lof = f - hf;               // exact (exponents adjacent)
        __bf16 l = (__bf16)lof;
        float lf = (float)l;
        hv[k] = h;
        lv[k] = l;
        rsum += f;
        lolo += lf * lf;
        mask |= pres_bit(f);
    }
    *(bf16x4*)hi = hv;
    *(bf16x4*)lo = lv;
}

// 256 blocks x 1024 threads, 1 block/CU. Block b owns K columns [b*512, b*512+512).
// 16 waves in a 4x4 grid; each wave computes a 64x64 output tile as 4x4 MFMA
// 16x16x32 tiles, 3 MFMA passes (hi*hi, hi*lo, lo*hi) into one fp32 accumulator.
__global__ __launch_bounds__(1024) void gram_kernel(
    const float* __restrict__ x,
    float* __restrict__ gpart,
    float* __restrict__ g32,
    float* __restrict__ rowsumPart,
    float* __restrict__ loloPart,
    unsigned long long* __restrict__ gpres,
    int pathA) {
    __shared__ __bf16 ldsHi[BR * LSTR];
    __shared__ __bf16 ldsLo[BR * LSTR];
    __shared__ float rsbuf[1024];
    __shared__ float lolobuf[1024];
    __shared__ unsigned long long maskbuf[1024];

    const int t = threadIdx.x;
    const int r = t >> 2;        // staging row (fixed per thread)
    const int q = t & 3;         // staging quarter within row
    const int lane = t & 63;
    const int wv = t >> 6;       // wave 0..15
    const int wr = wv >> 2;      // wave row tile group
    const int wc = wv & 3;       // wave col tile group
    const int fr = lane & 15;    // fragment row (A/B operand m/n index)
    const int fq = lane >> 4;    // fragment quad (k group)
    const int blk = blockIdx.x;

    const float* xrow = x + (size_t)r * DD + (size_t)blk * KBLK;

    f32x4 acc[4][4];
#pragma unroll
    for (int i = 0; i < 4; ++i)
#pragma unroll
        for (int j = 0; j < 4; ++j) acc[i][j] = (f32x4){0.f, 0.f, 0.f, 0.f};

    float rsum = 0.f, lolo = 0.f;
    unsigned long long mask = 0ull;

    // LDS fragment base pointers (A operand: lane holds A[m=lane&15][k=fq*8+j])
    const __bf16* aHi = ldsHi + (wr * 64 + fr) * LSTR + fq * 8;
    const __bf16* aLo = ldsLo + (wr * 64 + fr) * LSTR + fq * 8;
    const __bf16* bHi = ldsHi + (wc * 64 + fr) * LSTR + fq * 8;
    const __bf16* bLo = ldsLo + (wc * 64 + fr) * LSTR + fq * 8;

    // register prefetch of stage 0
    float4 pre0 = *(const float4*)(xrow + q * 4);
    float4 pre1 = *(const float4*)(xrow + q * 4 + 16);

    for (int s = 0; s < NSTG; ++s) {
        __syncthreads();   // prior stage's LDS reads complete
        conv4(pre0, &ldsHi[r * LSTR + q * 4], &ldsLo[r * LSTR + q * 4], rsum, lolo, mask);
        conv4(pre1, &ldsHi[r * LSTR + q * 4 + 16], &ldsLo[r * LSTR + q * 4 + 16], rsum, lolo, mask);
        __syncthreads();   // stage visible to all waves

        if (s + 1 < NSTG) {   // issue next stage's loads; latency hidden by MFMA phase
            pre0 = *(const float4*)(xrow + (s + 1) * KS + q * 4);
            pre1 = *(const float4*)(xrow + (s + 1) * KS + q * 4 + 16);
        }

        bf16x8 ah[4], al[4];
#pragma unroll
        for (int i = 0; i < 4; ++i) {
            ah[i] = *(const bf16x8*)(aHi + i * 16 * LSTR);
            al[i] = *(const bf16x8*)(aLo + i * 16 * LSTR);
        }
#pragma unroll
        for (int j = 0; j < 4; ++j) {
            bf16x8 bh = *(const bf16x8*)(bHi + j * 16 * LSTR);
            bf16x8 bl = *(const bf16x8*)(bLo + j * 16 * LSTR);
#pragma unroll
            for (int i = 0; i < 4; ++i) {
                acc[i][j] = __builtin_amdgcn_mfma_f32_16x16x32_bf16(ah[i], bh, acc[i][j], 0, 0, 0);
                acc[i][j] = __builtin_amdgcn_mfma_f32_16x16x32_bf16(ah[i], bl, acc[i][j], 0, 0, 0);
                acc[i][j] = __builtin_amdgcn_mfma_f32_16x16x32_bf16(al[i], bh, acc[i][j], 0, 0, 0);
            }
        }
    }

    // ---- rowsum / lolo / presence block reduction ----
    __syncthreads();
    rsbuf[t] = rsum;
    lolobuf[t] = lolo;
    maskbuf[t] = mask;
    __syncthreads();
    if (t < 256) {
        float s4 = rsbuf[4 * t] + rsbuf[4 * t + 1] + rsbuf[4 * t + 2] + rsbuf[4 * t + 3];
        float l4 = lolobuf[4 * t] + lolobuf[4 * t + 1] + lolobuf[4 * t + 2] + lolobuf[4 * t + 3];
        unsigned long long m4 = maskbuf[4 * t] | maskbuf[4 * t + 1] |
                                maskbuf[4 * t + 2] | maskbuf[4 * t + 3];
        rowsumPart[t * 256 + blk] = s4;          // [row][blk] for coalesced stats read
        loloPart[t * 256 + blk] = l4;
        atomicOr(&gpres[t], m4);
    }

    // ---- emit Gram tile: C/D layout col=lane&15, row=fq*4+reg (m89-verified) ----
    if (pathA) {
        float* dst = gpart + (size_t)blk * 65536;
#pragma unroll
        for (int i = 0; i < 4; ++i)
#pragma unroll
            for (int j = 0; j < 4; ++j) {
                int row = (wr * 4 + i) * 16 + fq * 4;
                int col = (wc * 4 + j) * 16 + fr;
#pragma unroll
                for (int reg = 0; reg < 4; ++reg)
                    dst[(row + reg) * 256 + col] = acc[i][j][reg];
            }
    } else {
#pragma unroll
        for (int i = 0; i < 4; ++i)
#pragma unroll
            for (int j = 0; j < 4; ++j) {
                int row = (wr * 4 + i) * 16 + fq * 4;
                int col = (wc * 4 + j) * 16 + fr;
#pragma unroll
                for (int reg = 0; reg < 4; ++reg)
                    atomicAdd(&g32[(row + reg) * 256 + col], acc[i][j][reg]);
            }
    }
}

// Block i: reduce 256 partial Grams for row i in fp64, write gf64 row, and
// compute per-row stats rs/sd/sumg/gii. 256 blocks x 256 threads.
__global__ __launch_bounds__(256) void gredstats_kernel(
    const float* __restrict__ gpart, const float* __restrict__ g32,
    const float* __restrict__ rsp, const float* __restrict__ lolop,
    double* __restrict__ gf64,
    double* __restrict__ rsRow, double* __restrict__ sdRow,
    double* __restrict__ sumgRow, double* __restrict__ giiRow,
    int pathA) {
    __shared__ double lds4[4];
    __shared__ double graw_sh;
    const int i = blockIdx.x;
    const int c = threadIdx.x;
    const double Dd = (double)DD;

    double s = 0.0;
    if (pathA) {
        const float* src = gpart + (size_t)i * 256 + c;
#pragma unroll 8
        for (int p = 0; p < 256; ++p) s += (double)src[(size_t)p * 65536];
    } else {
        s = (double)g32[i * 256 + c];
    }
    gf64[i * 256 + c] = s;
    if (c == i) graw_sh = s;

    double rs_part = (double)rsp[i * 256 + c];
    double lolo_part = (double)lolop[i * 256 + c];

    double sumg = block_reduce_add_d(s, lds4);
    double rs = block_reduce_add_d(rs_part, lds4);
    double lolo = block_reduce_add_d(lolo_part, lds4);

    if (c == 0) {
        double gii = graw_sh + lolo;
        double covii = (gii - rs * rs / Dd) / (Dd - 1.0);
        rsRow[i] = rs;
        sdRow[i] = sqrt(covii);
        sumgRow[i] = sumg;
        giiRow[i] = gii;
    }
}

// Block i: f1s[i] = mean_k |clip(corr_ik)|. 256 blocks x 256 threads.
__global__ __launch_bounds__(256) void f1_kernel(
    const double* __restrict__ gf64, const double* __restrict__ rsRow,
    const double* __restrict__ sdRow, double* __restrict__ f1sRow) {
    __shared__ double lds4[4];
    const int i = blockIdx.x;
    const int k = threadIdx.x;
    const double Dd = (double)DD;

    double gik = gf64[i * 256 + k];
    double rsi = rsRow[i], rsk = rsRow[k];
    double sdi = sdRow[i], sdk = sdRow[k];
    double cov = (gik - rsi * rsk / Dd) / (Dd - 1.0);
    double corr = cov / (sdi * sdk);
    corr = fmin(1.0, fmax(-1.0, corr));
    double f1 = block_reduce_add_d(fabs(corr), lds4);
    if (k == 0) f1sRow[i] = f1 / 256.0;
}

// Single block: total mse, uniques, candidates, p. All tree reductions.
__global__ __launch_bounds__(256) void final_kernel(
    const double* __restrict__ rsRow, const double* __restrict__ sumgRow,
    const double* __restrict__ giiRow, const double* __restrict__ f1sRow,
    const unsigned long long* __restrict__ pres,
    double* __restrict__ pscal) {
    __shared__ double lds4[4];
    __shared__ unsigned long long lds4u[4];
    const int t = threadIdx.x;
    const double Dd = (double)DD;

    double sumg = sumgRow[t];
    double S = block_reduce_add_d(sumg, lds4);
    double rmse = (giiRow[t] - (2.0 / 256.0) * sumg + S / (256.0 * 256.0)) / Dd;
    double tmse = block_reduce_add_d(rmse, lds4);

    unsigned long long m = pres[t];
    unsigned long long allm = block_reduce_or_u64(m, lds4u);
    double totu = (double)__popcll(allm);
    double f3 = (double)__popcll(m) / totu;

    double cand = (1.0 - f1sRow[t]) * (rmse / tmse) * f3;
    double p = block_reduce_max_d(cand, lds4);
    if (t == 0) {
        p = fmax(p, 0.0);
        pscal[0] = p;
        float* pf = (float*)(pscal + 1);
        pf[0] = (float)p;
        pf[1] = (float)(1.0 / (1.0 - p));
    }
}

__global__ __launch_bounds__(256) void dropout_kernel(
    const float4* __restrict__ x, const float4* __restrict__ n,
    float4* __restrict__ o, const double* __restrict__ pscal) {
    const float* pp = (const float*)(pscal + 1);
    const float pf = pp[0];
    const float inv = pp[1];
    int idx = blockIdx.x * 256 + threadIdx.x;
    float4 xv = x[idx];
    float4 nv = n[idx];
    float4 ov;
    ov.x = (nv.x >= pf) ? xv.x * inv : 0.0f;
    ov.y = (nv.y >= pf) ? xv.y * inv : 0.0f;
    ov.z = (nv.z >= pf) ? xv.z * inv : 0.0f;
    ov.w = (nv.w >= pf) ? xv.w * inv : 0.0f;
    o[idx] = ov;
}

extern "C" void kernel_launch(void* const* d_in, const int* in_sizes, int n_in,
                              void* d_out, int out_size, void* d_ws, size_t ws_size,
                              hipStream_t stream) {
    const float* x = (const float*)d_in[0];
    const float* noise = (const float*)d_in[1];
    float* out = (float*)d_out;
    char* ws = (char*)d_ws;

    unsigned long long* pres = (unsigned long long*)(ws + 0);
    double* pscal = (double*)(ws + 2048);
    double* rsRow = (double*)(ws + 4096);
    double* sdRow = (double*)(ws + 6144);
    double* sumgRow = (double*)(ws + 8192);
    double* giiRow = (double*)(ws + 10240);
    double* f1sRow = (double*)(ws + 12288);
    float* rsp = (float*)(ws + 16384);
    float* lolop = (float*)(ws + 278528);
    double* gf64 = (double*)(ws + 540672);
    float* gpart = (float*)(ws + 1064960);   // pathA (64 MB)
    float* g32 = (float*)(ws + 1064960);     // pathB

    const size_t needA = 1064960 + (size_t)256 * 65536 * sizeof(float);  // ~68.2 MB
    const int pathA = (ws_size >= needA) ? 1 : 0;

    init_kernel<<<64, 256, 0, stream>>>(pres, g32, !pathA);
    gram_kernel<<<BR, 1024, 0, stream>>>(x, gpart, g32, rsp, lolop, pres, pathA);
    gredstats_kernel<<<256, 256, 0, stream>>>(gpart, g32, rsp, lolop, gf64,
                                              rsRow, sdRow, sumgRow, giiRow, pathA);
    f1_kernel<<<256, 256, 0, stream>>>(gf64, rsRow, sdRow, f1sRow);
    final_kernel<<<1, 256, 0, stream>>>(rsRow, sumgRow, giiRow, f1sRow, pres, pscal);
    dropout_kernel<<<(BR * DD) / (4 * 256), 256, 0, stream>>>(
        (const float4*)x, (const float4*)noise, (float4*)out, pscal);
}